// Round 2
// baseline (721.836 us; speedup 1.0000x reference)
//
#include <hip/hip_runtime.h>
#include <hip/hip_fp16.h>

#define N_ROWS 8191
#define NO 8092
#define GSTRIDE 8192
#define SEG 512
#define WARM 48
#define CHUNK 32
#define LPAD 33
#define LROWS (CHUNK + 255)

#define OUT_UU  65480464ul
#define OUT_KF  65488655ul
#define OUT_KDF 65496846ul

#define WS_XB   134217728ul
#define WS_DIAG 136314880ul
#define WS_Q    136347648ul

typedef short bf16x8 __attribute__((ext_vector_type(8)));
typedef float f32x4  __attribute__((ext_vector_type(4)));

__device__ __forceinline__ float asin_core(float a) {
    // a in [-1+eps, 1-eps]; Cephes asinf, branch-free select
    float ax  = fabsf(a);
    bool  big = ax > 0.5f;
    float z   = big ? 0.5f * (1.0f - ax) : ax * ax;
    float x   = big ? sqrtf(z) : ax;
    float p = fmaf(z, 4.2163199048e-2f, 2.4181311049e-2f);
    p = fmaf(p, z, 4.5470025998e-2f);
    p = fmaf(p, z, 7.4953002686e-2f);
    p = fmaf(p, z, 1.6666752422e-1f);
    p = fmaf(p * z, x, x);
    float r = big ? fmaf(-2.0f, p, 1.57079632679489662f) : p;
    return copysignf(r, a);
}

// m is pre-doubled: m = (sqrt2*q[t]) * (sqrt2*q[t+c]) = 2 q q
__device__ __forceinline__ float kstep(float g, float kp, float m) {
    float uv  = fmaf(0.5f, g, fmaf(0.9f, kp, 0.1f));
    float arg = uv * m;
    arg = fminf(fmaxf(arg, -0.999999f), 0.999999f);
    return 0.63661977236758134f * asin_core(arg);
}

__device__ __forceinline__ unsigned short f2bf(float f) {
    unsigned int u = __float_as_uint(f);
    u = (u + 0x7FFFu + ((u >> 16) & 1u)) >> 16;
    return (unsigned short)u;
}

// ---- kernel 1: fused convert (fp32 -> bf16, pad row 8191) + row norms ----
__global__ void k_prep(const float* __restrict__ X, unsigned short* __restrict__ Xb,
                       float* __restrict__ diag) {
    int gw   = (blockIdx.x * 256 + threadIdx.x) >> 6;   // 0..8191, one wave per row
    int lane = threadIdx.x & 63;
    unsigned int* Xb32 = (unsigned int*)Xb;
    if (gw >= N_ROWS) {                                  // row 8191: zero pad
        Xb32[(size_t)gw * 64 + lane] = 0u;
        return;
    }
    const float2* row = (const float2*)(X + (size_t)gw * 128);
    float2 v = row[lane];
    unsigned int packed = (unsigned int)f2bf(v.x) | ((unsigned int)f2bf(v.y) << 16);
    Xb32[(size_t)gw * 64 + lane] = packed;
    float s = fmaf(v.x, v.x, v.y * v.y);
    #pragma unroll
    for (int off = 32; off > 0; off >>= 1) s += __shfl_xor(s, off, 64);
    if (lane == 0) diag[gw] = s;
}

// ---- kernel 2: diag scan (segmented, contraction lookahead) -> uu, q, k_diag_final ----
__global__ void k_scan_diag(const float* __restrict__ diag, float* __restrict__ q,
                            float* __restrict__ d_out) {
    int tid = threadIdx.x;                 // 256 threads, 32 outputs each
    int t0  = tid * 32;
    int tw  = max(0, t0 - 32);
    int te  = min(t0 + 32, N_ROWS);
    float kp = 0.0f;
    for (int t = tw; t < te; ++t) {
        float dg = diag[t];
        float uv = fmaf(0.5f, dg, fmaf(0.9f, kp, 0.1f));
        float s  = fabsf(fmaf(2.0f, uv, 1.0f));
        float arg = (uv + uv) / s;
        arg = fminf(fmaxf(arg, -0.999999f), 0.999999f);
        float k = 0.63661977236758134f * asin_core(arg);
        if (t >= t0) {
            d_out[OUT_UU + t] = uv;
            q[t] = 1.41421356237309515f / sqrtf(s);      // sqrt(2)/sqrt(s): folds the 2x into m
            if (t == N_ROWS - 1) d_out[OUT_KDF] = k;
        }
        kp = k;
    }
    // zero-pad q[8191..8446] so out-of-range q[t+c] reads in the scan kernels
    // (lanes whose outputs are discarded) hit initialized memory
    q[N_ROWS + tid] = 0.0f;
}

// ---- kernel 3: gram = Xb Xb^T (upper-tri 128x128 tiles, bf16 MFMA, fp16 out) ----
#define GP 136
__global__ __launch_bounds__(256) void k_gemm(const unsigned short* __restrict__ Xb,
                                              __half* __restrict__ gram) {
    int bi = blockIdx.y, bj = blockIdx.x;
    if (bj < bi) return;
    __shared__ short As[128 * GP];
    __shared__ short Bs[128 * GP];
    int tid = threadIdx.x;
    const uint4* ga = (const uint4*)(Xb + (size_t)bi * 128 * 128);
    const uint4* gb = (const uint4*)(Xb + (size_t)bj * 128 * 128);
    #pragma unroll
    for (int p = 0; p < 8; ++p) {
        int chunk = tid + p * 256;           // 2048 chunks of 16B per tile
        int row = chunk >> 4, c8 = chunk & 15;
        uint4 va = ga[row * 16 + c8];
        *(uint4*)&As[row * GP + c8 * 8] = va;
        uint4 vb = gb[row * 16 + c8];
        *(uint4*)&Bs[row * GP + c8 * 8] = vb;
    }
    __syncthreads();

    int lane = tid & 63, wave = tid >> 6;
    int wm = wave & 1, wn = wave >> 1;
    int lr = lane & 15, lk = lane >> 4;
    f32x4 acc[4][4];
    #pragma unroll
    for (int mi = 0; mi < 4; ++mi)
        #pragma unroll
        for (int ni = 0; ni < 4; ++ni) acc[mi][ni] = (f32x4){0.f, 0.f, 0.f, 0.f};

    #pragma unroll
    for (int kc = 0; kc < 4; ++kc) {
        bf16x8 a[4], b[4];
        #pragma unroll
        for (int mi = 0; mi < 4; ++mi)
            a[mi] = *(bf16x8*)&As[(wm * 64 + mi * 16 + lr) * GP + kc * 32 + lk * 8];
        #pragma unroll
        for (int ni = 0; ni < 4; ++ni)
            b[ni] = *(bf16x8*)&Bs[(wn * 64 + ni * 16 + lr) * GP + kc * 32 + lk * 8];
        #pragma unroll
        for (int mi = 0; mi < 4; ++mi)
            #pragma unroll
            for (int ni = 0; ni < 4; ++ni)
                acc[mi][ni] = __builtin_amdgcn_mfma_f32_16x16x32_bf16(a[mi], b[ni], acc[mi][ni], 0, 0, 0);
    }

    // C/D layout (m89-verified): col = lane&15, row = (lane>>4)*4 + reg
    int row0 = (lane >> 4) * 4, col = lane & 15;
    #pragma unroll
    for (int mi = 0; mi < 4; ++mi) {
        #pragma unroll
        for (int ni = 0; ni < 4; ++ni) {
            size_t gi = (size_t)bi * 128 + wm * 64 + mi * 16 + row0;
            size_t gj = (size_t)bj * 128 + wn * 64 + ni * 16 + col;
            f32x4 v = acc[mi][ni];
            #pragma unroll
            for (int r = 0; r < 4; ++r)
                gram[(gi + r) * GSTRIDE + gj] = __float2half(v[r]);
        }
    }
}

// ---- kernel 4: main diagonal-chain scan (upper triangle) + fused mirror ----
// Each 32-t chunk of outputs is staged in a skewed LDS tile; lower-triangle
// (transposed) elements are then written as coalesced row segments.
// LDS slot for element (ti, tid): lt[(ti+tid)*LPAD + ti]
//   write banks: (tid + 2*ti) % 32  -> 2 lanes/bank (free)
//   read  banks: (s + ti) % 32      -> conflict-free
__global__ __launch_bounds__(256) void k_scan_main(const __half* __restrict__ gram,
                                                   const float* __restrict__ q,
                                                   float* __restrict__ d_out) {
    __shared__ float lt[LROWS * LPAD];       // 287*33*4 = 37884 B -> 2 blocks/CU
    int tid = threadIdx.x;
    int c0  = blockIdx.x * 256;
    int t0  = 99 + blockIdx.y * SEG;
    int tlim0 = N_ROWS - c0;                 // block-max tlim (lane c0)
    if (t0 >= tlim0) return;                 // block-uniform: safe with syncthreads
    int tmax = min(t0 + SEG, tlim0);
    int c = c0 + tid;
    int lane = tid & 63, wave = tid >> 6;
    int sh = lane >> 5, l31 = lane & 31;

    float kp = 0.0f;
    int tw = t0 - WARM;
    size_t gidx = (size_t)tw * (GSTRIDE + 1) + (size_t)c;
    #pragma unroll 4
    for (int t = tw; t < t0; ++t, gidx += (GSTRIDE + 1)) {
        float g = __half2float(gram[gidx]);
        float m = q[t] * q[t + c];
        kp = kstep(g, kp, m);
    }

    size_t oidx = (size_t)(t0 - 99) * NO + (size_t)(t0 + c - 99);
    for (int tg = t0; tg < tmax; tg += CHUNK) {
        int tch = min(CHUNK, tmax - tg);
        // --- scan phase: compute chain, direct coalesced upper store + LDS stage ---
        #pragma unroll 4
        for (int ti = 0; ti < tch; ++ti) {
            int t = tg + ti;
            float g = __half2float(gram[gidx]);
            float m = q[t] * q[t + c];
            kp = kstep(g, kp, m);
            float v = fmaf(0.1f, g, kp);
            lt[(ti + tid) * LPAD + ti] = v;
            if (t + c < N_ROWS) {                       // lane-valid (t < tlim(c))
                d_out[oidx] = v;
                if (t + c == N_ROWS - 1) d_out[OUT_KF + t] = kp;   // k_final via symmetry
            }
            gidx += (GSTRIDE + 1);
            oidx += (NO + 1);
        }
        __syncthreads();
        // --- transpose phase: emit lower triangle as coalesced row segments ---
        int smax  = tch + 255;               // output rows rbase..rbase+smax-1
        int rbase = tg + c0 - 99;
        int cb    = tg - 99;
        for (int sb = (wave << 1) + sh; sb < smax; sb += 8) {
            int ti0 = max(0, sb - 255);
            int tie = min(tch - 1, sb);      // inclusive
            int t_i = ti0 + l31;
            int row_g = rbase + sb;
            // valid element && in-bounds row && strictly-lower (c>0)
            if (t_i <= tie && row_g < NO && (sb - t_i + c0) > 0) {
                d_out[(size_t)row_g * NO + (size_t)(cb + t_i)] = lt[sb * LPAD + t_i];
            }
        }
        __syncthreads();
    }
}

// ---- kernel 5: short diagonals (c >= 8092) only feed k_final[0..98], exact from t=0 ----
__global__ void k_short_diag(const __half* __restrict__ gram, const float* __restrict__ q,
                             float* __restrict__ d_out) {
    int l = threadIdx.x;
    if (l > 98) return;
    int c = NO + l;                 // 8092..8190
    int tl = N_ROWS - c;            // 1..99
    float kp = 0.0f;
    size_t gidx = (size_t)c;
    for (int t = 0; t < tl; ++t, gidx += (GSTRIDE + 1)) {
        float g = __half2float(gram[gidx]);
        float m = q[t] * q[t + c];
        kp = kstep(g, kp, m);
    }
    d_out[OUT_KF + (tl - 1)] = kp;
}

extern "C" void kernel_launch(void* const* d_in, const int* in_sizes, int n_in,
                              void* d_out, int out_size, void* d_ws, size_t ws_size,
                              hipStream_t stream) {
    const float* X = (const float*)d_in[0];
    float* out = (float*)d_out;
    char* ws = (char*)d_ws;
    __half* gram = (__half*)ws;
    unsigned short* Xb = (unsigned short*)(ws + WS_XB);
    float* diag = (float*)(ws + WS_DIAG);
    float* q = (float*)(ws + WS_Q);

    k_prep<<<dim3(2048), dim3(256), 0, stream>>>(X, Xb, diag);
    k_scan_diag<<<dim3(1), dim3(256), 0, stream>>>(diag, q, out);
    k_gemm<<<dim3(64, 64), dim3(256), 0, stream>>>(Xb, gram);
    k_scan_main<<<dim3(32, 16), dim3(256), 0, stream>>>(gram, q, out);
    k_short_diag<<<dim3(1), dim3(128), 0, stream>>>(gram, q, out);
}

// Round 3
// 474.538 us; speedup vs baseline: 1.5211x; 1.5211x over previous
//
#include <hip/hip_runtime.h>
#include <hip/hip_fp16.h>

#define N_ROWS 8191
#define NO 8092
#define GSTRIDE 8192
#define SEG 256
#define WARM 32
#define CHUNK 32
#define LPAD 33
#define LROWS (CHUNK + 255)

#define OUT_UU  65480464ul
#define OUT_KF  65488655ul
#define OUT_KDF 65496846ul

#define WS_XB   134217728ul
#define WS_DIAG 136314880ul
#define WS_Q    136347648ul

typedef short bf16x8 __attribute__((ext_vector_type(8)));
typedef float f32x4  __attribute__((ext_vector_type(4)));

__device__ __forceinline__ float asin_core(float a) {
    // a in [-1+eps, 1-eps]; Cephes asinf, branch-free select
    float ax  = fabsf(a);
    bool  big = ax > 0.5f;
    float z   = big ? 0.5f * (1.0f - ax) : ax * ax;
    float x   = big ? sqrtf(z) : ax;
    float p = fmaf(z, 4.2163199048e-2f, 2.4181311049e-2f);
    p = fmaf(p, z, 4.5470025998e-2f);
    p = fmaf(p, z, 7.4953002686e-2f);
    p = fmaf(p, z, 1.6666752422e-1f);
    p = fmaf(p * z, x, x);
    float r = big ? fmaf(-2.0f, p, 1.57079632679489662f) : p;
    return copysignf(r, a);
}

// chain step with precomputed a1 = 0.9*m, a0 = m*(0.5*g + 0.1)
__device__ __forceinline__ float kchain(float a1, float a0, float kp) {
    float arg = fmaf(a1, kp, a0);
    arg = fminf(fmaxf(arg, -0.999999f), 0.999999f);
    return 0.63661977236758134f * asin_core(arg);
}

__device__ __forceinline__ float kstep(float g, float kp, float m) {
    float uv  = fmaf(0.5f, g, fmaf(0.9f, kp, 0.1f));
    float arg = uv * m;
    arg = fminf(fmaxf(arg, -0.999999f), 0.999999f);
    return 0.63661977236758134f * asin_core(arg);
}

__device__ __forceinline__ unsigned short f2bf(float f) {
    unsigned int u = __float_as_uint(f);
    u = (u + 0x7FFFu + ((u >> 16) & 1u)) >> 16;
    return (unsigned short)u;
}

// ---- kernel 1: fused convert (fp32 -> bf16, pad row 8191) + row norms ----
__global__ void k_prep(const float* __restrict__ X, unsigned short* __restrict__ Xb,
                       float* __restrict__ diag) {
    int gw   = (blockIdx.x * 256 + threadIdx.x) >> 6;   // 0..8191, one wave per row
    int lane = threadIdx.x & 63;
    unsigned int* Xb32 = (unsigned int*)Xb;
    if (gw >= N_ROWS) {                                  // row 8191: zero pad
        Xb32[(size_t)gw * 64 + lane] = 0u;
        return;
    }
    const float2* row = (const float2*)(X + (size_t)gw * 128);
    float2 v = row[lane];
    unsigned int packed = (unsigned int)f2bf(v.x) | ((unsigned int)f2bf(v.y) << 16);
    Xb32[(size_t)gw * 64 + lane] = packed;
    float s = fmaf(v.x, v.x, v.y * v.y);
    #pragma unroll
    for (int off = 32; off > 0; off >>= 1) s += __shfl_xor(s, off, 64);
    if (lane == 0) diag[gw] = s;
}

// ---- kernel 2: diag scan -> uu, q, k_diag_final (register-prefetched) ----
__global__ void k_scan_diag(const float* __restrict__ diag, float* __restrict__ q,
                            float* __restrict__ d_out) {
    int tid = threadIdx.x;                 // 256 threads, 32 outputs each
    int t0  = tid * 32;
    int tw  = max(0, t0 - 32);
    int te  = min(t0 + 32, N_ROWS);
    // prefetch 64 consecutive diag values as 16 float4 (tw is 32-float aligned)
    float dv[64];
    const f32x4* dp = (const f32x4*)(diag + tw);
    #pragma unroll
    for (int i = 0; i < 16; ++i) {
        f32x4 v4 = dp[i];
        dv[i * 4 + 0] = v4[0]; dv[i * 4 + 1] = v4[1];
        dv[i * 4 + 2] = v4[2]; dv[i * 4 + 3] = v4[3];
    }
    float kp = 0.0f;
    #pragma unroll
    for (int i = 0; i < 64; ++i) {
        int t = tw + i;
        float dg = dv[i];
        float uv = fmaf(0.5f, dg, fmaf(0.9f, kp, 0.1f));
        float s  = fabsf(fmaf(2.0f, uv, 1.0f));
        float arg = (uv + uv) / s;
        arg = fminf(fmaxf(arg, -0.999999f), 0.999999f);
        float k = 0.63661977236758134f * asin_core(arg);
        if (t >= t0 && t < te) {
            d_out[OUT_UU + t] = uv;
            q[t] = 1.41421356237309515f / sqrtf(s);      // sqrt(2)/sqrt(s): folds 2x into m
            if (t == N_ROWS - 1) d_out[OUT_KDF] = k;
        }
        kp = k;
    }
    // zero-pad q[8191..8446]: out-of-range q reads (discarded lanes) hit zeros
    q[N_ROWS + tid] = 0.0f;
}

// ---- kernel 3: gram = Xb Xb^T (upper-tri 128x128 tiles, bf16 MFMA, fp16 out) ----
#define GP 136
__global__ __launch_bounds__(256) void k_gemm(const unsigned short* __restrict__ Xb,
                                              __half* __restrict__ gram) {
    int bi = blockIdx.y, bj = blockIdx.x;
    if (bj < bi) return;
    __shared__ short As[128 * GP];
    __shared__ short Bs[128 * GP];
    int tid = threadIdx.x;
    const uint4* ga = (const uint4*)(Xb + (size_t)bi * 128 * 128);
    const uint4* gb = (const uint4*)(Xb + (size_t)bj * 128 * 128);
    #pragma unroll
    for (int p = 0; p < 8; ++p) {
        int chunk = tid + p * 256;           // 2048 chunks of 16B per tile
        int row = chunk >> 4, c8 = chunk & 15;
        uint4 va = ga[row * 16 + c8];
        *(uint4*)&As[row * GP + c8 * 8] = va;
        uint4 vb = gb[row * 16 + c8];
        *(uint4*)&Bs[row * GP + c8 * 8] = vb;
    }
    __syncthreads();

    int lane = tid & 63, wave = tid >> 6;
    int wm = wave & 1, wn = wave >> 1;
    int lr = lane & 15, lk = lane >> 4;
    f32x4 acc[4][4];
    #pragma unroll
    for (int mi = 0; mi < 4; ++mi)
        #pragma unroll
        for (int ni = 0; ni < 4; ++ni) acc[mi][ni] = (f32x4){0.f, 0.f, 0.f, 0.f};

    #pragma unroll
    for (int kc = 0; kc < 4; ++kc) {
        bf16x8 a[4], b[4];
        #pragma unroll
        for (int mi = 0; mi < 4; ++mi)
            a[mi] = *(bf16x8*)&As[(wm * 64 + mi * 16 + lr) * GP + kc * 32 + lk * 8];
        #pragma unroll
        for (int ni = 0; ni < 4; ++ni)
            b[ni] = *(bf16x8*)&Bs[(wn * 64 + ni * 16 + lr) * GP + kc * 32 + lk * 8];
        #pragma unroll
        for (int mi = 0; mi < 4; ++mi)
            #pragma unroll
            for (int ni = 0; ni < 4; ++ni)
                acc[mi][ni] = __builtin_amdgcn_mfma_f32_16x16x32_bf16(a[mi], b[ni], acc[mi][ni], 0, 0, 0);
    }

    // C/D layout (m89-verified): col = lane&15, row = (lane>>4)*4 + reg
    int row0 = (lane >> 4) * 4, col = lane & 15;
    #pragma unroll
    for (int mi = 0; mi < 4; ++mi) {
        #pragma unroll
        for (int ni = 0; ni < 4; ++ni) {
            size_t gi = (size_t)bi * 128 + wm * 64 + mi * 16 + row0;
            size_t gj = (size_t)bj * 128 + wn * 64 + ni * 16 + col;
            f32x4 v = acc[mi][ni];
            #pragma unroll
            for (int r = 0; r < 4; ++r)
                gram[(gi + r) * GSTRIDE + gj] = __float2half(v[r]);
        }
    }
}

// ---- kernel 4: main scan (upper) + fused mirror, register-batch prefetch ----
// All chunk loops are constant-trip (CHUNK=32) with static register indexing;
// validity is enforced by store predicates only. Over-reads past gram land in
// the Xb region (in-workspace); q reads are clamped into its zero-pad.
__global__ __launch_bounds__(256) void k_scan_main(const __half* __restrict__ gram,
                                                   const float* __restrict__ q,
                                                   float* __restrict__ d_out) {
    __shared__ float lt[LROWS * LPAD];       // 287*33*4 = 37884 B
    int tid = threadIdx.x;
    int c0  = blockIdx.x * 256;
    int t0  = 99 + blockIdx.y * SEG;
    int tlim0 = N_ROWS - c0;                 // block-max exclusive t bound
    if (t0 >= tlim0) return;                 // block-uniform exit
    int tmax = min(t0 + SEG, tlim0);
    int c = c0 + tid;
    int lane = tid & 63, wave = tid >> 6;
    int sh = lane >> 5, l31 = lane & 31;

    float gv[CHUNK], a1v[CHUNK], a0v[CHUNK];
    float kp = 0.0f;

    // ---- warm chunk (32 steps, no stores): batch prefetch + chain ----
    {
        int tw = t0 - WARM;
        size_t gidx = (size_t)tw * (GSTRIDE + 1) + (size_t)c;
        #pragma unroll
        for (int ti = 0; ti < CHUNK; ++ti)
            gv[ti] = __half2float(gram[gidx + (size_t)ti * (GSTRIDE + 1)]);
        #pragma unroll
        for (int ti = 0; ti < CHUNK; ++ti) {
            int t = tw + ti;
            float m = q[t] * q[min(t + c, N_ROWS)];
            a1v[ti] = 0.9f * m;
            a0v[ti] = m * fmaf(0.5f, gv[ti], 0.1f);
        }
        #pragma unroll
        for (int ti = 0; ti < CHUNK; ++ti)
            kp = kchain(a1v[ti], a0v[ti], kp);
    }

    size_t gbase = (size_t)t0 * (GSTRIDE + 1) + (size_t)c;
    size_t oidx  = (size_t)(t0 - 99) * NO + (size_t)(t0 + c - 99);
    for (int tg = t0; tg < tmax; tg += CHUNK) {
        int tch = min(CHUNK, tmax - tg);     // only < CHUNK in the final chunk
        // --- prefetch 32 gram values + precompute chain coefficients ---
        #pragma unroll
        for (int ti = 0; ti < CHUNK; ++ti)
            gv[ti] = __half2float(gram[gbase + (size_t)ti * (GSTRIDE + 1)]);
        #pragma unroll
        for (int ti = 0; ti < CHUNK; ++ti) {
            int t = tg + ti;
            float m = q[t] * q[min(t + c, N_ROWS)];
            a1v[ti] = 0.9f * m;
            a0v[ti] = m * fmaf(0.5f, gv[ti], 0.1f);
        }
        // --- serial chain + coalesced upper store + LDS stage ---
        #pragma unroll
        for (int ti = 0; ti < CHUNK; ++ti) {
            int t = tg + ti;
            kp = kchain(a1v[ti], a0v[ti], kp);
            float v = fmaf(0.1f, gv[ti], kp);
            lt[(ti + tid) * LPAD + ti] = v;
            if (t + c < N_ROWS) {            // implies t < tmax (see proof r2)
                d_out[oidx + (size_t)ti * (NO + 1)] = v;
                if (t + c == N_ROWS - 1) d_out[OUT_KF + t] = kp;
            }
        }
        __syncthreads();
        // --- transpose phase: lower triangle as coalesced row segments ---
        int rbase = tg + c0 - 99;
        int cb    = tg - 99;
        for (int sb = (wave << 1) + sh; sb < LROWS; sb += 8) {
            int ti0 = max(0, sb - 255);
            int tie = min(tch - 1, sb);      // inclusive; tch guards partial chunk
            int t_i = ti0 + l31;
            int row_g = rbase + sb;
            // in-range element && in-bounds row (== element validity) && strict-lower
            if (t_i <= tie && row_g < NO && (sb - t_i + c0) > 0) {
                d_out[(size_t)row_g * NO + (size_t)(cb + t_i)] = lt[sb * LPAD + t_i];
            }
        }
        __syncthreads();
        gbase += (size_t)CHUNK * (GSTRIDE + 1);
        oidx  += (size_t)CHUNK * (NO + 1);
    }
}

// ---- kernel 5: short diagonals (c >= 8092) -> k_final[0..98], prefetched ----
#define SD_B 33
__global__ void k_short_diag(const __half* __restrict__ gram, const float* __restrict__ q,
                             float* __restrict__ d_out) {
    int l = threadIdx.x;
    if (l > 98) return;
    int c = NO + l;                 // 8092..8190
    int tl = N_ROWS - c;            // 1..99
    float kp = 0.0f, kpf = 0.0f;
    float gvs[SD_B];
    for (int b = 0; b < 3; ++b) {
        int tb = b * SD_B;
        size_t gidx = (size_t)tb * (GSTRIDE + 1) + (size_t)c;
        #pragma unroll
        for (int i = 0; i < SD_B; ++i)      // t < 99 always in-bounds of gram
            gvs[i] = __half2float(gram[gidx + (size_t)i * (GSTRIDE + 1)]);
        #pragma unroll
        for (int i = 0; i < SD_B; ++i) {
            int t = tb + i;
            float m = q[t] * q[min(t + c, N_ROWS)];
            kp = kstep(gvs[i], kp, m);
            if (t == tl - 1) kpf = kp;
        }
    }
    d_out[OUT_KF + (tl - 1)] = kpf;
}

extern "C" void kernel_launch(void* const* d_in, const int* in_sizes, int n_in,
                              void* d_out, int out_size, void* d_ws, size_t ws_size,
                              hipStream_t stream) {
    const float* X = (const float*)d_in[0];
    float* out = (float*)d_out;
    char* ws = (char*)d_ws;
    __half* gram = (__half*)ws;
    unsigned short* Xb = (unsigned short*)(ws + WS_XB);
    float* diag = (float*)(ws + WS_DIAG);
    float* q = (float*)(ws + WS_Q);

    k_prep<<<dim3(2048), dim3(256), 0, stream>>>(X, Xb, diag);
    k_scan_diag<<<dim3(1), dim3(256), 0, stream>>>(diag, q, out);
    k_gemm<<<dim3(64, 64), dim3(256), 0, stream>>>(Xb, gram);
    k_scan_main<<<dim3(32, 32), dim3(256), 0, stream>>>(gram, q, out);
    k_short_diag<<<dim3(1), dim3(128), 0, stream>>>(gram, q, out);
}